// Round 1
// baseline (106.036 us; speedup 1.0000x reference)
//
#include <hip/hip_runtime.h>

// FVNet: B=8, F=512, N=512, K=32, all fp32.
//   xt = transpose(x,(0,2,1));  a = softmax(xt@W.T + b, axis=2)   (B,N,K)
//   asum = sum_n a                                               (B,K)
//   ax  = einsum('bnk,bnf->bfk', a, xt)                          (B,F,K)
//   ax2 = einsum('bnk,bnf->bfk', a, xt*xt)                       (B,F,K)
//   fv1 = (ax - mu*asum)/sigma ; fv2 = (ax2 - 2mu*ax + mu^2*asum)/sigma^2 - asum
//   l2norm over K per (b,f), then l2norm over (F*K) per b == /sqrt(512) exactly
//   out = concat([fv1, fv2], axis=1)  -> (B, 2*F*K) fp32, out_size=262144
//
// Workspace layout (floats): aP[131072] | axP[4*131072] | ax2P[4*131072] | asum[256]
// (~4.5 MB; everything written before read each launch, no zero-init needed.)

#define B_ 8
#define F_ 512
#define N_ 512
#define K_ 32

// ---------------- Kernel 1: a = softmax(x^T W^T + b) over K ----------------
// grid = B * (N/32) = 128 blocks, 256 threads.
// Each block: one batch b, 32 n's, all 32 k's; f staged in chunks of 64.
__global__ __launch_bounds__(256) void k_a(const float* __restrict__ x,
                                           const float* __restrict__ W,
                                           const float* __restrict__ bias,
                                           float* __restrict__ aP) {
  __shared__ __align__(16) float xs[64][33];   // [f][n], +1 pad -> conflict-free
  __shared__ __align__(16) float ws[32][68];   // [k][f], row stride 272B (16B mult)
  __shared__ float ls[32][33];                 // logits [n][k]
  __shared__ float linv[32];
  const int t  = threadIdx.x;
  const int b  = blockIdx.x >> 4;
  const int n0 = (blockIdx.x & 15) << 5;
  const int nl = t & 31;   // n within tile
  const int kq = t >> 5;   // k quad 0..7

  float acc[4];
#pragma unroll
  for (int j = 0; j < 4; ++j) acc[j] = bias[kq * 4 + j];

  for (int fc = 0; fc < F_; fc += 64) {
    // stage x[b, fc:fc+64, n0:n0+32]  (coalesced 128B runs)
#pragma unroll
    for (int i = 0; i < 8; ++i) {
      int flat = t + 256 * i;
      int fi = flat >> 5, nn = flat & 31;
      xs[fi][nn] = x[(size_t)(b * F_ + fc + fi) * N_ + n0 + nn];
    }
    // stage W[0:32, fc:fc+64]
#pragma unroll
    for (int i = 0; i < 8; ++i) {
      int flat = t + 256 * i;
      int k = flat >> 6, fj = flat & 63;
      ws[k][fj] = W[k * F_ + fc + fj];
    }
    __syncthreads();
#pragma unroll 4
    for (int fi = 0; fi < 64; fi += 4) {
      float x0 = xs[fi + 0][nl], x1 = xs[fi + 1][nl];
      float x2 = xs[fi + 2][nl], x3 = xs[fi + 3][nl];
#pragma unroll
      for (int j = 0; j < 4; ++j) {
        const float4 w = *(const float4*)&ws[kq * 4 + j][fi];
        acc[j] += x0 * w.x + x1 * w.y + x2 * w.z + x3 * w.w;
      }
    }
    __syncthreads();
  }

  // softmax over 32 k per n
#pragma unroll
  for (int j = 0; j < 4; ++j) ls[nl][kq * 4 + j] = acc[j];
  __syncthreads();
  if (t < 32) {
    float m = -1e30f;
#pragma unroll
    for (int k = 0; k < 32; ++k) m = fmaxf(m, ls[t][k]);
    float s = 0.f;
#pragma unroll
    for (int k = 0; k < 32; ++k) {
      float e = __expf(ls[t][k] - m);
      ls[t][k] = e;
      s += e;
    }
    linv[t] = 1.f / s;
  }
  __syncthreads();
  const float inv = linv[nl];
  float4 av;
  av.x = ls[nl][kq * 4 + 0] * inv;
  av.y = ls[nl][kq * 4 + 1] * inv;
  av.z = ls[nl][kq * 4 + 2] * inv;
  av.w = ls[nl][kq * 4 + 3] * inv;
  *(float4*)&aP[(size_t)(b * N_ + n0 + nl) * K_ + kq * 4] = av;
}

// ---------------- Kernel 2: asum[b,k] = sum_n a[b,n,k] ----------------
// grid = 8 (one per batch), 256 threads
__global__ __launch_bounds__(256) void k_asum(const float* __restrict__ aP,
                                              float* __restrict__ asum) {
  __shared__ float ps[8][32];
  const int b = blockIdx.x;
  const int t = threadIdx.x;
  const int k = t & 31;
  const int ng = t >> 5;
  float s = 0.f;
#pragma unroll 4
  for (int i = 0; i < 64; ++i) {
    int n = ng * 64 + i;
    s += aP[(size_t)(b * N_ + n) * K_ + k];
  }
  ps[ng][k] = s;
  __syncthreads();
  if (t < 32) {
    float tot = 0.f;
#pragma unroll
    for (int g = 0; g < 8; ++g) tot += ps[g][t];
    asum[b * K_ + t] = tot;
  }
}

// ---------------- Kernel 3: ax / ax2 partial GEMMs ----------------
// grid = B * 16 ftiles * 4 nsplits = 512 blocks, 256 threads.
// Each block: f-tile of 32, all 32 k, 128 n; writes one partial slice s.
__global__ __launch_bounds__(256) void k_ax(const float* __restrict__ x,
                                            const float* __restrict__ aP,
                                            float* __restrict__ axP,
                                            float* __restrict__ ax2P) {
  __shared__ float xs[32][34];   // [f][n], stride 34 (8B align + bank spread)
  __shared__ float as_[32][34];  // [n][k]
  const int t   = threadIdx.x;
  const int s   = blockIdx.x & 3;
  const int ft  = (blockIdx.x >> 2) & 15;
  const int b   = blockIdx.x >> 6;
  const int f0  = ft << 5;
  const int nb  = s << 7;     // n range base (128 per split)
  const int fq  = t & 15;     // f-pair index
  const int kq  = t >> 4;     // k-pair index
  const int fa  = fq * 2;

  float ax00 = 0, ax01 = 0, ax10 = 0, ax11 = 0;
  float b00 = 0, b01 = 0, b10 = 0, b11 = 0;

  for (int c = 0; c < 4; ++c) {
    const int n0 = nb + c * 32;
#pragma unroll
    for (int i = 0; i < 4; ++i) {
      int flat = t + 256 * i;
      int r = flat >> 5, q = flat & 31;
      xs[r][q]  = x[(size_t)(b * F_ + f0 + r) * N_ + n0 + q];
      as_[r][q] = aP[(size_t)(b * N_ + n0 + r) * K_ + q];
    }
    __syncthreads();
#pragma unroll 8
    for (int n = 0; n < 32; n += 2) {
      float2 xa = *(const float2*)&xs[fa][n];
      float2 xb = *(const float2*)&xs[fa + 1][n];
      float2 a0 = *(const float2*)&as_[n][kq * 2];
      float2 a1 = *(const float2*)&as_[n + 1][kq * 2];
      // n
      ax00 += xa.x * a0.x; ax01 += xa.x * a0.y;
      ax10 += xb.x * a0.x; ax11 += xb.x * a0.y;
      float sa = xa.x * xa.x, sb = xb.x * xb.x;
      b00 += sa * a0.x; b01 += sa * a0.y;
      b10 += sb * a0.x; b11 += sb * a0.y;
      // n+1
      ax00 += xa.y * a1.x; ax01 += xa.y * a1.y;
      ax10 += xb.y * a1.x; ax11 += xb.y * a1.y;
      sa = xa.y * xa.y; sb = xb.y * xb.y;
      b00 += sa * a1.x; b01 += sa * a1.y;
      b10 += sb * a1.x; b11 += sb * a1.y;
    }
    __syncthreads();
  }

  const int f1 = f0 + fa;
  const int kk = kq * 2;
  const size_t base = (size_t)(s * B_ + b) * F_;
  float2 v;
  v.x = ax00; v.y = ax01; *(float2*)&axP [(base + f1    ) * K_ + kk] = v;
  v.x = ax10; v.y = ax11; *(float2*)&axP [(base + f1 + 1) * K_ + kk] = v;
  v.x = b00;  v.y = b01;  *(float2*)&ax2P[(base + f1    ) * K_ + kk] = v;
  v.x = b10;  v.y = b11;  *(float2*)&ax2P[(base + f1 + 1) * K_ + kk] = v;
}

// ---------------- Kernel 4: fv1/fv2 + normalizations ----------------
// grid = B*F*K/256 = 512 blocks. One thread per (b,f,k).
// Row (K-axis) norm via half-wave shuffle; global per-b norm == sqrt(512)
// (every K-row is unit norm after the first normalization; rows are O(10),
//  never near the 1e-12 clamp).
__global__ __launch_bounds__(256) void k_fv(const float* __restrict__ axP,
                                            const float* __restrict__ ax2P,
                                            const float* __restrict__ asum,
                                            const float* __restrict__ mu,
                                            const float* __restrict__ sg,
                                            float* __restrict__ out) {
  const int g = blockIdx.x * 256 + threadIdx.x;
  const int k = g & 31;
  const int f = (g >> 5) & (F_ - 1);
  const int b = g >> 14;

  float ax = 0.f, ax2 = 0.f;
#pragma unroll
  for (int s = 0; s < 4; ++s) {
    ax  += axP [(size_t)((s * B_ + b) * F_ + f) * K_ + k];
    ax2 += ax2P[(size_t)((s * B_ + b) * F_ + f) * K_ + k];
  }
  const float m  = mu[f * K_ + k];
  const float sd = sg[f * K_ + k];
  const float as = asum[b * K_ + k];

  const float fv1 = (ax - m * as) / sd;
  const float fv2 = (ax2 - 2.f * m * ax + m * m * as) / (sd * sd) - as;

  float s1 = fv1 * fv1, s2 = fv2 * fv2;
#pragma unroll
  for (int off = 16; off >= 1; off >>= 1) {
    s1 += __shfl_xor(s1, off, 32);
    s2 += __shfl_xor(s2, off, 32);
  }
  const float inv512 = 0.04419417382415922f;  // 1/sqrt(512)
  const float o1 = fv1 / fmaxf(sqrtf(s1), 1e-12f) * inv512;
  const float o2 = fv2 / fmaxf(sqrtf(s2), 1e-12f) * inv512;

  out[(size_t)b * (2 * F_ * K_) + f * K_ + k] = o1;
  out[(size_t)b * (2 * F_ * K_) + F_ * K_ + f * K_ + k] = o2;
}

extern "C" void kernel_launch(void* const* d_in, const int* in_sizes, int n_in,
                              void* d_out, int out_size, void* d_ws, size_t ws_size,
                              hipStream_t stream) {
  const float* x  = (const float*)d_in[0];
  const float* W  = (const float*)d_in[1];
  const float* bv = (const float*)d_in[2];
  const float* mu = (const float*)d_in[3];
  const float* sg = (const float*)d_in[4];
  float* out = (float*)d_out;

  float* ws   = (float*)d_ws;
  float* aP   = ws;                         // B*N*K       = 131072
  float* axP  = ws + 131072;                // 4*B*F*K     = 524288
  float* ax2P = ws + 131072 + 524288;       // 4*B*F*K     = 524288
  float* asum = ws + 131072 + 2 * 524288;   // B*K         = 256

  hipLaunchKernelGGL(k_a,    dim3(128), dim3(256), 0, stream, x, W, bv, aP);
  hipLaunchKernelGGL(k_asum, dim3(8),   dim3(256), 0, stream, aP, asum);
  hipLaunchKernelGGL(k_ax,   dim3(512), dim3(256), 0, stream, x, aP, axP, ax2P);
  hipLaunchKernelGGL(k_fv,   dim3(512), dim3(256), 0, stream, axP, ax2P, asum, mu, sg, out);
}

// Round 2
// 86.386 us; speedup vs baseline: 1.2275x; 1.2275x over previous
//
#include <hip/hip_runtime.h>

// FVNet: B=8, F=512, N=512, K=32, fp32.
//   a = softmax(x^T W^T + b, axis=k)  (B,N,K)
//   asum = sum_n a; ax = sum_n a*x; ax2 = sum_n a*x^2   (per b,f,k)
//   fv1/fv2 + per-(b,f) K-row l2norm + per-b l2norm (== /sqrt(512) exactly,
//   since all 512 K-rows are unit-norm after the first normalization).
//
// Round-2 structure: 3 dispatches, all 256+ blocks, register-tiled to cut
// LDS-port pressure (fp32 vector GEMM is LDS-issue-bound on CDNA4).
// ws floats: aP[131072] | axP[8*131072] | ax2P[8*131072] | asumP[8192]

#define B_ 8
#define F_ 512
#define N_ 512
#define K_ 32

// ---------------- Kernel 1: logits + softmax + a + asum partials ----------
// grid = B * 32 ntiles (16 n each) = 256 blocks, 256 threads.
// Threads: (fs 0..7) x (kg 0..7) x (ng 0..3); thread tile 4n x 4k over a
// 64-f slice (8-way f-split, combined via LDS reduction).
__global__ __launch_bounds__(256) void k_a(const float* __restrict__ x,
                                           const float* __restrict__ W,
                                           const float* __restrict__ bias,
                                           float* __restrict__ aP,
                                           float* __restrict__ asumP) {
  __shared__ float xs[128][18];   // [f][n]  (phase-resident 128 f)
  __shared__ float ws[128][36];   // [f][k]  transposed W, b128-aligned rows
  __shared__ float red[512][9];   // [n*32+k][fs partials]; col 8 = scalar slot
  __shared__ float rmax[16], rinv[16];
  const int t  = threadIdx.x;
  const int b  = blockIdx.x >> 5;
  const int nt = blockIdx.x & 31;
  const int n0 = nt << 4;
  const int fs = t >> 5;          // 0..7 f-split lane
  const int kg = (t >> 2) & 7;    // 0..7 -> 4k
  const int ng = t & 3;           // 0..3 -> 4n
  const int n4 = ng * 4, k4 = kg * 4;

  float acc[4][4] = {{0.f}};

  for (int ph = 0; ph < 4; ++ph) {
    const int fb = ph << 7;
    // stage x[b, fb:fb+128, n0:n0+16]
#pragma unroll
    for (int it = 0; it < 8; ++it) {
      int flat = t + 256 * it;
      int f = flat >> 4, nn = flat & 15;
      xs[f][nn] = x[(size_t)(b * F_ + fb + f) * N_ + n0 + nn];
    }
    // stage W[0:32, fb:fb+128] transposed -> ws[f][k]
#pragma unroll
    for (int it = 0; it < 16; ++it) {
      int flat = t + 256 * it;
      int k = flat >> 7, f = flat & 127;
      ws[f][k] = W[k * F_ + fb + f];
    }
    __syncthreads();
    const int fBeg = fs << 4;   // this thread's 16-f slice of the phase
#pragma unroll
    for (int fi = 0; fi < 16; ++fi) {
      const int f = fBeg + fi;
      const float2 x01 = *(const float2*)&xs[f][n4];
      const float2 x23 = *(const float2*)&xs[f][n4 + 2];
      const float4 wv  = *(const float4*)&ws[f][k4];
      acc[0][0] += x01.x * wv.x; acc[0][1] += x01.x * wv.y;
      acc[0][2] += x01.x * wv.z; acc[0][3] += x01.x * wv.w;
      acc[1][0] += x01.y * wv.x; acc[1][1] += x01.y * wv.y;
      acc[1][2] += x01.y * wv.z; acc[1][3] += x01.y * wv.w;
      acc[2][0] += x23.x * wv.x; acc[2][1] += x23.x * wv.y;
      acc[2][2] += x23.x * wv.z; acc[2][3] += x23.x * wv.w;
      acc[3][0] += x23.y * wv.x; acc[3][1] += x23.y * wv.y;
      acc[3][2] += x23.y * wv.z; acc[3][3] += x23.y * wv.w;
    }
    __syncthreads();
  }

  // dump partials: red[(nloc*32 + k)][fs]
#pragma unroll
  for (int i = 0; i < 4; ++i)
#pragma unroll
    for (int j = 0; j < 4; ++j)
      red[(n4 + i) * 32 + k4 + j][fs] = acc[i][j];
  __syncthreads();

  // combine 8 partials + bias; each thread owns outs {2t, 2t+1} (same n-row)
  const int o0 = 2 * t, o1 = 2 * t + 1;
  float l0 = bias[o0 & 31], l1 = bias[o1 & 31];
#pragma unroll
  for (int s = 0; s < 8; ++s) { l0 += red[o0][s]; l1 += red[o1][s]; }
  red[o0][8] = l0;   // distinct column, no race with partial reads
  red[o1][8] = l1;
  __syncthreads();

  if (t < 16) {   // softmax stats per n-row
    float m = -1e30f;
#pragma unroll
    for (int j = 0; j < 32; ++j) m = fmaxf(m, red[t * 32 + j][8]);
    float ssum = 0.f;
#pragma unroll
    for (int j = 0; j < 32; ++j) ssum += __expf(red[t * 32 + j][8] - m);
    rmax[t] = m;
    rinv[t] = 1.f / ssum;
  }
  __syncthreads();

  const int row = o0 >> 5;           // o1 is the same row (o0 even)
  const float m = rmax[row], inv = rinv[row];
  const float a0 = __expf(l0 - m) * inv;
  const float a1 = __expf(l1 - m) * inv;
  float2 av; av.x = a0; av.y = a1;
  *(float2*)&aP[(size_t)(b * N_ + n0 + row) * K_ + (o0 & 31)] = av;

  red[o0][8] = a0;   // reuse col 8 for asum partial (stats reads are done)
  red[o1][8] = a1;
  __syncthreads();
  if (t < 32) {
    float s = 0.f;
#pragma unroll
    for (int nl = 0; nl < 16; ++nl) s += red[nl * 32 + t][8];
    asumP[(b * 32 + nt) * 32 + t] = s;
  }
}

// ---------------- Kernel 2: ax / ax2 partial GEMMs ----------------
// grid = B * 4 ftiles(128 f) * 8 nsplits(64 n) = 256 blocks, 256 threads.
// Threads: (fg 0..31) x (kg 0..7); thread tile 4f x 4k, 32 accumulators.
// x staged transposed [n][f] so one b128 feeds 4 f; a staged [n][k].
__global__ __launch_bounds__(256) void k_ax(const float* __restrict__ x,
                                            const float* __restrict__ aP,
                                            float* __restrict__ axP,
                                            float* __restrict__ ax2P) {
  __shared__ float xsT[64][132];   // [n][f], 528B rows (16B-aligned b128)
  __shared__ float as_[64][36];    // [n][k]
  const int t  = threadIdx.x;
  const int s  = blockIdx.x & 7;
  const int ft = (blockIdx.x >> 3) & 3;
  const int b  = blockIdx.x >> 5;
  const int f0 = ft << 7;
  const int n0 = s << 6;
  const int fg = t >> 3, kg = t & 7;
  const int f4 = fg * 4, k4 = kg * 4;

  // stage x[b, f0:f0+128, n0:n0+64] -> xsT[n][f]
#pragma unroll
  for (int it = 0; it < 32; ++it) {
    int flat = t + 256 * it;
    int r = flat >> 6, nn = flat & 63;
    xsT[nn][r] = x[(size_t)(b * F_ + f0 + r) * N_ + n0 + nn];
  }
  // stage a[b, n0:n0+64, :]
#pragma unroll
  for (int it = 0; it < 8; ++it) {
    int flat = t + 256 * it;
    int r = flat >> 5, kk = flat & 31;
    as_[r][kk] = aP[(size_t)(b * N_ + n0 + r) * K_ + kk];
  }
  __syncthreads();

  float ax[4][4] = {{0.f}}, bx[4][4] = {{0.f}};
#pragma unroll 4
  for (int n = 0; n < 64; ++n) {
    const float4 xv = *(const float4*)&xsT[n][f4];
    const float4 av = *(const float4*)&as_[n][k4];
    const float* xp = &xv.x;
    const float* ap = &av.x;
#pragma unroll
    for (int i = 0; i < 4; ++i) {
      const float xi = xp[i];
      const float xq = xi * xi;
#pragma unroll
      for (int j = 0; j < 4; ++j) {
        ax[i][j] += xi * ap[j];
        bx[i][j] += xq * ap[j];
      }
    }
  }

  const size_t base = ((size_t)(s * B_ + b) * F_ + f0 + f4) * K_ + k4;
#pragma unroll
  for (int i = 0; i < 4; ++i) {
    float4 v1, v2;
    v1.x = ax[i][0]; v1.y = ax[i][1]; v1.z = ax[i][2]; v1.w = ax[i][3];
    v2.x = bx[i][0]; v2.y = bx[i][1]; v2.z = bx[i][2]; v2.w = bx[i][3];
    *(float4*)&axP [base + (size_t)i * K_] = v1;
    *(float4*)&ax2P[base + (size_t)i * K_] = v2;
  }
}

// ---------------- Kernel 3: fv1/fv2 + normalizations ----------------
// grid = 512 blocks, 1 thread per (b,f,k). Row-norm via 32-wide shuffle;
// per-b global norm == 1/sqrt(512) analytically.
__global__ __launch_bounds__(256) void k_fv(const float* __restrict__ axP,
                                            const float* __restrict__ ax2P,
                                            const float* __restrict__ asumP,
                                            const float* __restrict__ mu,
                                            const float* __restrict__ sg,
                                            float* __restrict__ out) {
  __shared__ float sm[32];
  const int t = threadIdx.x;
  const int g = blockIdx.x * 256 + t;
  const int k = g & 31;
  const int f = (g >> 5) & (F_ - 1);
  const int b = g >> 14;

  if (t < 32) {  // block-wide asum[b][k] (b uniform per block)
    float s = 0.f;
#pragma unroll
    for (int nt = 0; nt < 32; ++nt) s += asumP[(b * 32 + nt) * 32 + t];
    sm[t] = s;
  }
  __syncthreads();

  float ax = 0.f, ax2 = 0.f;
#pragma unroll
  for (int s = 0; s < 8; ++s) {
    ax  += axP [(size_t)((s * B_ + b) * F_ + f) * K_ + k];
    ax2 += ax2P[(size_t)((s * B_ + b) * F_ + f) * K_ + k];
  }
  const float m  = mu[f * K_ + k];
  const float sd = sg[f * K_ + k];
  const float as = sm[k];

  const float fv1 = (ax - m * as) / sd;
  const float fv2 = (ax2 - 2.f * m * ax + m * m * as) / (sd * sd) - as;

  float s1 = fv1 * fv1, s2 = fv2 * fv2;
#pragma unroll
  for (int off = 16; off >= 1; off >>= 1) {
    s1 += __shfl_xor(s1, off, 32);
    s2 += __shfl_xor(s2, off, 32);
  }
  const float inv512 = 0.04419417382415922f;  // 1/sqrt(512)
  const float o1 = fv1 / fmaxf(sqrtf(s1), 1e-12f) * inv512;
  const float o2 = fv2 / fmaxf(sqrtf(s2), 1e-12f) * inv512;

  out[(size_t)b * (2 * F_ * K_) + f * K_ + k] = o1;
  out[(size_t)b * (2 * F_ * K_) + F_ * K_ + f * K_ + k] = o2;
}

extern "C" void kernel_launch(void* const* d_in, const int* in_sizes, int n_in,
                              void* d_out, int out_size, void* d_ws, size_t ws_size,
                              hipStream_t stream) {
  const float* x  = (const float*)d_in[0];
  const float* W  = (const float*)d_in[1];
  const float* bv = (const float*)d_in[2];
  const float* mu = (const float*)d_in[3];
  const float* sg = (const float*)d_in[4];
  float* out = (float*)d_out;

  float* ws    = (float*)d_ws;
  float* aP    = ws;                          // B*N*K          = 131072
  float* axP   = ws + 131072;                 // 8*B*F*K        = 1048576
  float* ax2P  = ws + 131072 + 1048576;       // 8*B*F*K        = 1048576
  float* asumP = ws + 131072 + 2 * 1048576;   // B*32*K         = 8192

  hipLaunchKernelGGL(k_a,  dim3(256), dim3(256), 0, stream, x, W, bv, aP, asumP);
  hipLaunchKernelGGL(k_ax, dim3(256), dim3(256), 0, stream, x, aP, axP, ax2P);
  hipLaunchKernelGGL(k_fv, dim3(512), dim3(256), 0, stream, axP, ax2P, asumP, mu, sg, out);
}